// Round 8
// baseline (282.481 us; speedup 1.0000x reference)
//
#include <hip/hip_runtime.h>
#include <hip/hip_bf16.h>
#include <math.h>

#define N_NODES 50000
#define N_EDGES 640000
#define HEADS 4
#define CDIM 32
#define HC 128          // HEADS*CDIM
#define DIN 128
#define DOUT 32
#define NEG_SLOPE 0.2f
#define TPAD 136        // 128 + 8 bf16 pad -> 2-way bank aliasing (free)
#define SCAN_B 256
#define SCAN_NB ((N_NODES + SCAN_B - 1) / SCAN_B)   // 196
#define CNT_NB (N_EDGES / 256)                      // 2500

typedef __hip_bfloat16 bf16;
typedef __attribute__((ext_vector_type(8))) short short8;
typedef __attribute__((ext_vector_type(4))) float floatx4;

static __device__ __forceinline__ float bflo(unsigned w) { return __uint_as_float(w << 16); }
static __device__ __forceinline__ float bfhi(unsigned w) { return __uint_as_float(w & 0xFFFF0000u); }
static __device__ __forceinline__ unsigned short f2bf(float f) {
    union { bf16 h; unsigned short u; } cv; cv.h = __float2bfloat16(f); return cv.u;
}

// Fused prep: in-degree count (blocks 0..2499) + Wl/Wr bf16 conversion
// (blocks 2500..2627) + cvec = bias@Wp + bp (block 2628).
__global__ __launch_bounds__(256) void k_prep(
    const int* __restrict__ ei, unsigned* __restrict__ deg,
    const float* __restrict__ Wl, const float* __restrict__ Wr,
    const float* __restrict__ bias, const float* __restrict__ Wp,
    const float* __restrict__ bp,
    bf16* __restrict__ Wlb, bf16* __restrict__ Wrb, float* __restrict__ cvec)
{
    const int b = blockIdx.x, t = threadIdx.x;
    if (b < CNT_NB) {
        atomicAdd(&deg[ei[N_EDGES + b * 256 + t]], 1u);
    } else if (b < CNT_NB + 64) {
        const int i = (b - CNT_NB) * 256 + t;
        Wlb[i] = __float2bfloat16(Wl[i]);
    } else if (b < CNT_NB + 128) {
        const int i = (b - CNT_NB - 64) * 256 + t;
        Wrb[i] = __float2bfloat16(Wr[i]);
    } else if (t < DOUT) {
        float v = bp[t];
        for (int c = 0; c < HC; c++) v += bias[c] * Wp[c * DOUT + t];
        cvec[t] = v;
    }
}

// Phase 1: xl = x@Wl then xr = x@Wr in ONE pass over x (staged once).
// 64 nodes/block, 4 waves; A-fragments held in registers across both halves.
__global__ __launch_bounds__(256) void k_transform(
    const float* __restrict__ x,
    const bf16* __restrict__ Wlb,
    const bf16* __restrict__ Wrb,
    bf16* __restrict__ xl, bf16* __restrict__ xr)
{
    __shared__ __align__(16) unsigned short xs[64][TPAD];
    __shared__ __align__(16) unsigned short Ws[128][TPAD];
    const int t = threadIdx.x;
    const int n0 = blockIdx.x * 64;

    for (int i = t; i < 64 * DIN; i += 256) {
        int n = i >> 7, c = i & 127;
        xs[n][c] = (n0 + n < N_NODES) ? f2bf(x[(size_t)(n0 + n) * DIN + c]) : 0;
    }
    const unsigned* __restrict__ WuL = (const unsigned*)Wlb;
    for (int i = t; i < DIN * HC / 2; i += 256) {
        const unsigned u = WuL[i];
        const int l = 2 * i, c = l >> 7, j = l & 127;
        Ws[j][c]     = (unsigned short)(u & 0xFFFFu);
        Ws[j + 1][c] = (unsigned short)(u >> 16);
    }
    __syncthreads();

    const int w = t >> 6, lane = t & 63;
    const int m = lane & 15, quad = lane >> 4;

    short8 af[4];
    #pragma unroll
    for (int kk = 0; kk < 4; kk++)
        af[kk] = *(const short8*)&xs[w * 16 + m][kk * 32 + quad * 8];

    #pragma unroll
    for (int jt = 0; jt < 8; jt++) {
        floatx4 acc = {0.f, 0.f, 0.f, 0.f};
        #pragma unroll
        for (int kk = 0; kk < 4; kk++) {
            short8 bfr = *(const short8*)&Ws[jt * 16 + m][kk * 32 + quad * 8];
            acc = __builtin_amdgcn_mfma_f32_16x16x32_bf16(af[kk], bfr, acc, 0, 0, 0);
        }
        #pragma unroll
        for (int r = 0; r < 4; r++) {               // C/D: col=m, row=quad*4+r
            int n = n0 + w * 16 + quad * 4 + r;
            if (n < N_NODES)
                xl[(size_t)n * HC + jt * 16 + m] = __float2bfloat16(acc[r]);
        }
    }
    __syncthreads();                                // all waves done with Ws

    const unsigned* __restrict__ WuR = (const unsigned*)Wrb;
    for (int i = t; i < DIN * HC / 2; i += 256) {
        const unsigned u = WuR[i];
        const int l = 2 * i, c = l >> 7, j = l & 127;
        Ws[j][c]     = (unsigned short)(u & 0xFFFFu);
        Ws[j + 1][c] = (unsigned short)(u >> 16);
    }
    __syncthreads();

    #pragma unroll
    for (int jt = 0; jt < 8; jt++) {
        floatx4 acc = {0.f, 0.f, 0.f, 0.f};
        #pragma unroll
        for (int kk = 0; kk < 4; kk++) {
            short8 bfr = *(const short8*)&Ws[jt * 16 + m][kk * 32 + quad * 8];
            acc = __builtin_amdgcn_mfma_f32_16x16x32_bf16(af[kk], bfr, acc, 0, 0, 0);
        }
        #pragma unroll
        for (int r = 0; r < 4; r++) {
            int n = n0 + w * 16 + quad * 4 + r;
            if (n < N_NODES)
                xr[(size_t)n * HC + jt * 16 + m] = __float2bfloat16(acc[r]);
        }
    }
}

// Scan stage 1: block-local exclusive scan + per-block sums.
__global__ __launch_bounds__(SCAN_B) void k_scan1(
    const unsigned* __restrict__ deg, unsigned* __restrict__ offs,
    unsigned* __restrict__ bsum)
{
    __shared__ unsigned sh[SCAN_B];
    const int t = threadIdx.x, i = blockIdx.x * SCAN_B + t;
    const unsigned d = (i < N_NODES) ? deg[i] : 0u;
    sh[t] = d;
    __syncthreads();
    for (int off = 1; off < SCAN_B; off <<= 1) {
        unsigned v = (t >= off) ? sh[t - off] : 0u;
        __syncthreads();
        sh[t] += v;
        __syncthreads();
    }
    if (i < N_NODES) offs[i] = sh[t] - d;           // block-local exclusive
    if (t == SCAN_B - 1) bsum[blockIdx.x] = sh[t];
}

// Scan stage 2+3 fused: each block reduces its own prefix of bsum (196 u32,
// trivial) and adds the base; writes final offs + cursor.
__global__ __launch_bounds__(SCAN_B) void k_scan23(
    unsigned* __restrict__ offs, const unsigned* __restrict__ bsum,
    unsigned* __restrict__ cursor)
{
    __shared__ unsigned red[SCAN_B];
    const int t = threadIdx.x;
    red[t] = (t < SCAN_NB && t < blockIdx.x) ? bsum[t] : 0u;
    __syncthreads();
    for (int off = SCAN_B / 2; off > 0; off >>= 1) {
        if (t < off) red[t] += red[t + off];
        __syncthreads();
    }
    const unsigned base = red[0];
    const int i = blockIdx.x * SCAN_B + t;
    if (i < N_NODES) {
        const unsigned v = offs[i] + base;
        offs[i] = v;
        cursor[i] = v;
    }
    if (i == 0) offs[N_NODES] = N_EDGES;
}

// Bucket src ids by dst.
__global__ __launch_bounds__(256) void k_fill(
    const int* __restrict__ ei, unsigned* __restrict__ cursor,
    int* __restrict__ srcs)
{
    const int e = blockIdx.x * 256 + threadIdx.x;   // grid == E exactly
    const int dst = ei[N_EDGES + e];
    const unsigned pos = atomicAdd(&cursor[dst], 1u);
    srcs[pos] = ei[e];
}

// Fused logit + exp + aggregate + projection, single gather sweep,
// TWO edges per wave-iteration. Lane = (half = lane>>5, cl = lane&31);
// lane owns cols 4cl..4cl+3 (head h = cl>>3); halves process alternating
// edges; per-head logit = 3 shuffle-adds over the 8-lane group; halves
// combined once per node via xor-32.
__global__ __launch_bounds__(256) void k_agg(
    const int* __restrict__ srcs, const unsigned* __restrict__ offs,
    const unsigned* __restrict__ xl2,   // bf16 xl as uint pairs [N][64]
    const unsigned* __restrict__ xr2,   // bf16 xr as uint pairs [N][64]
    const float* __restrict__ att,
    const float* __restrict__ Wp, const float* __restrict__ cvec,
    float* __restrict__ out)
{
    __shared__ float sWp[HC][DOUT];     // 16 KB
    __shared__ float srow[4][HC];
    const int t = threadIdx.x;
    for (int i = t; i < HC * DOUT; i += 256)
        ((float*)sWp)[i] = Wp[i];
    __syncthreads();

    const int w = t >> 6, lane = t & 63;
    const int node = blockIdx.x * 4 + w;
    const int half = lane >> 5, cl = lane & 31;
    const int c0 = 4 * cl;

    const uint2 xrw = *((const uint2*)(xr2 + node * 64) + cl);
    const float xr0 = bflo(xrw.x), xr1 = bfhi(xrw.x);
    const float xr2v = bflo(xrw.y), xr3 = bfhi(xrw.y);
    const float4 av = *(const float4*)(att + c0);

    const unsigned lo = offs[node], hi = offs[node + 1];
    float s_run = 0.f, acc0 = 0.f, acc1 = 0.f, acc2 = 0.f, acc3 = 0.f;

    for (unsigned base = lo; base < hi; base += 64) {
        const unsigned j = base + lane;
        const int srcj = (j < hi) ? srcs[j] : 0;
        const int cnt = (int)((hi - base < 64u) ? (hi - base) : 64u);
        uint2 xw[4];
        #pragma unroll
        for (int q = 0; q < 4; q++) {               // preload pairs 0..3
            const int eq = 2 * q + half;
            const int sj = __shfl(srcj, eq, 64);
            xw[q] = *((const uint2*)(xl2 + ((unsigned)((eq < cnt) ? sj : 0) << 6)) + cl);
        }
        for (int i = 0; i < cnt; i += 2) {
            const int q = (i >> 1) & 3;
            const uint2 cur = xw[q];
            const int ii = i + 8 + half;            // refill 4 pairs ahead
            const int sj = __shfl(srcj, ii & 63, 64);
            xw[q] = *((const uint2*)(xl2 + ((unsigned)((ii < cnt) ? sj : 0) << 6)) + cl);

            const float x0 = bflo(cur.x), x1 = bfhi(cur.x);
            const float x2 = bflo(cur.y), x3 = bfhi(cur.y);
            float v0 = x0 + xr0, v1 = x1 + xr1, v2 = x2 + xr2v, v3 = x3 + xr3;
            v0 = fmaxf(v0, NEG_SLOPE * v0);
            v1 = fmaxf(v1, NEG_SLOPE * v1);
            v2 = fmaxf(v2, NEG_SLOPE * v2);
            v3 = fmaxf(v3, NEG_SLOPE * v3);
            float p = av.x * v0 + av.y * v1 + av.z * v2 + av.w * v3;
            p += __shfl_xor(p, 1, 64);
            p += __shfl_xor(p, 2, 64);
            p += __shfl_xor(p, 4, 64);              // logit for (edge i+half, head)
            const float e_ = (i + half < cnt) ? __expf(p) : 0.f;
            s_run += e_;
            acc0 += x0 * e_;
            acc1 += x1 * e_;
            acc2 += x2 * e_;
            acc3 += x3 * e_;
        }
    }
    // combine the two halves (same cols, disjoint edge sets)
    s_run += __shfl_xor(s_run, 32, 64);
    acc0 += __shfl_xor(acc0, 32, 64);
    acc1 += __shfl_xor(acc1, 32, 64);
    acc2 += __shfl_xor(acc2, 32, 64);
    acc3 += __shfl_xor(acc3, 32, 64);
    const float rden = 1.f / (s_run + 1e-16f);

    if (half == 0) {
        float4 r = {acc0 * rden, acc1 * rden, acc2 * rden, acc3 * rden};
        *(float4*)&srow[w][c0] = r;
    }
    // same-wave LDS RAW: in-order DS pipe, no barrier needed
    const int jj = lane & 31;
    float pacc = 0.f;
    const int cb = half * 64;
    #pragma unroll 8
    for (int c = 0; c < 64; c++)
        pacc += srow[w][cb + c] * sWp[cb + c][jj];
    pacc += __shfl_down(pacc, 32, 64);
    if (lane < 32)
        out[(size_t)node * DOUT + jj] = pacc + cvec[jj];
}

extern "C" void kernel_launch(void* const* d_in, const int* in_sizes, int n_in,
                              void* d_out, int out_size, void* d_ws, size_t ws_size,
                              hipStream_t stream)
{
    const float* x    = (const float*)d_in[0];
    const int*   ei   = (const int*)d_in[1];
    const float* Wl   = (const float*)d_in[2];
    const float* Wr   = (const float*)d_in[3];
    const float* att  = (const float*)d_in[4];
    const float* bias = (const float*)d_in[5];
    const float* Wp   = (const float*)d_in[6];
    const float* bp   = (const float*)d_in[7];
    float* out = (float*)d_out;

    // workspace (~28.6 MB):
    // xl bf16[N*HC] | xr bf16[N*HC] | Wlb bf16[DIN*HC] | Wrb bf16[DIN*HC]
    // | cvec f32[32] | deg/cursor u32[N] | offs u32[N+1] | bsum u32[256]
    // | srcs i32[E]
    bf16* xl       = (bf16*)d_ws;
    bf16* xr       = xl + (size_t)N_NODES * HC;
    bf16* Wlb      = xr + (size_t)N_NODES * HC;
    bf16* Wrb      = Wlb + DIN * HC;
    float* cvec    = (float*)(Wrb + DIN * HC);
    unsigned* deg  = (unsigned*)(cvec + DOUT);
    unsigned* offs = deg + N_NODES;
    unsigned* bsum = offs + (N_NODES + 1);
    int* srcs      = (int*)(bsum + 256);

    hipMemsetAsync(deg, 0, (size_t)N_NODES * sizeof(unsigned), stream);

    k_prep<<<CNT_NB + 129, 256, 0, stream>>>(ei, deg, Wl, Wr, bias, Wp, bp,
                                             Wlb, Wrb, cvec);
    k_transform<<<(N_NODES + 63) / 64, 256, 0, stream>>>(x, Wlb, Wrb, xl, xr);
    k_scan1<<<SCAN_NB, SCAN_B, 0, stream>>>(deg, offs, bsum);
    k_scan23<<<SCAN_NB, SCAN_B, 0, stream>>>(offs, bsum, deg);  // deg = cursor
    k_fill<<<N_EDGES / 256, 256, 0, stream>>>(ei, deg, srcs);
    k_agg<<<N_NODES / 4, 256, 0, stream>>>(srcs, offs,
        (const unsigned*)xl, (const unsigned*)xr, att, Wp, cvec, out);
}

// Round 9
// 239.315 us; speedup vs baseline: 1.1804x; 1.1804x over previous
//
#include <hip/hip_runtime.h>
#include <hip/hip_bf16.h>
#include <math.h>

#define N_NODES 50000
#define N_EDGES 640000
#define HEADS 4
#define CDIM 32
#define HC 128          // HEADS*CDIM
#define DIN 128
#define DOUT 32
#define NEG_SLOPE 0.2f
#define TPAD 136        // 128 + 8 bf16 pad -> 2-way bank aliasing (free)
#define SCAN_B 256
#define SCAN_NB ((N_NODES + SCAN_B - 1) / SCAN_B)   // 196
#define CNT_NB (N_EDGES / 256)                      // 2500

typedef __hip_bfloat16 bf16;
typedef __attribute__((ext_vector_type(8))) short short8;
typedef __attribute__((ext_vector_type(4))) float floatx4;

static __device__ __forceinline__ float bflo(unsigned w) { return __uint_as_float(w << 16); }
static __device__ __forceinline__ float bfhi(unsigned w) { return __uint_as_float(w & 0xFFFF0000u); }
static __device__ __forceinline__ unsigned short f2bf(float f) {
    union { bf16 h; unsigned short u; } cv; cv.h = __float2bfloat16(f); return cv.u;
}

// Fused prep: in-degree count (blocks 0..2499) + Wl/Wr bf16 conversion
// (blocks 2500..2627) + cvec = bias@Wp + bp (block 2628).
__global__ __launch_bounds__(256) void k_prep(
    const int* __restrict__ ei, unsigned* __restrict__ deg,
    const float* __restrict__ Wl, const float* __restrict__ Wr,
    const float* __restrict__ bias, const float* __restrict__ Wp,
    const float* __restrict__ bp,
    bf16* __restrict__ Wlb, bf16* __restrict__ Wrb, float* __restrict__ cvec)
{
    const int b = blockIdx.x, t = threadIdx.x;
    if (b < CNT_NB) {
        atomicAdd(&deg[ei[N_EDGES + b * 256 + t]], 1u);
    } else if (b < CNT_NB + 64) {
        const int i = (b - CNT_NB) * 256 + t;
        Wlb[i] = __float2bfloat16(Wl[i]);
    } else if (b < CNT_NB + 128) {
        const int i = (b - CNT_NB - 64) * 256 + t;
        Wrb[i] = __float2bfloat16(Wr[i]);
    } else if (t < DOUT) {
        float v = bp[t];
        for (int c = 0; c < HC; c++) v += bias[c] * Wp[c * DOUT + t];
        cvec[t] = v;
    }
}

// Phase 1: xl = x@Wl then xr = x@Wr in ONE pass over x (staged once).
// 64 nodes/block, 4 waves; A-fragments held in registers across both halves.
__global__ __launch_bounds__(256) void k_transform(
    const float* __restrict__ x,
    const bf16* __restrict__ Wlb,
    const bf16* __restrict__ Wrb,
    bf16* __restrict__ xl, bf16* __restrict__ xr)
{
    __shared__ __align__(16) unsigned short xs[64][TPAD];
    __shared__ __align__(16) unsigned short Ws[128][TPAD];
    const int t = threadIdx.x;
    const int n0 = blockIdx.x * 64;

    // float4-vectorized x staging: 2048 float4 loads per block
    for (int i = t; i < 64 * DIN / 4; i += 256) {
        const int n = i >> 5, c4 = (i & 31) * 4;
        float4 v = make_float4(0.f, 0.f, 0.f, 0.f);
        if (n0 + n < N_NODES)
            v = *(const float4*)(x + (size_t)(n0 + n) * DIN + c4);
        xs[n][c4]     = f2bf(v.x);
        xs[n][c4 + 1] = f2bf(v.y);
        xs[n][c4 + 2] = f2bf(v.z);
        xs[n][c4 + 3] = f2bf(v.w);
    }
    const unsigned* __restrict__ WuL = (const unsigned*)Wlb;
    for (int i = t; i < DIN * HC / 2; i += 256) {
        const unsigned u = WuL[i];
        const int l = 2 * i, c = l >> 7, j = l & 127;
        Ws[j][c]     = (unsigned short)(u & 0xFFFFu);
        Ws[j + 1][c] = (unsigned short)(u >> 16);
    }
    __syncthreads();

    const int w = t >> 6, lane = t & 63;
    const int m = lane & 15, quad = lane >> 4;

    short8 af[4];
    #pragma unroll
    for (int kk = 0; kk < 4; kk++)
        af[kk] = *(const short8*)&xs[w * 16 + m][kk * 32 + quad * 8];

    #pragma unroll
    for (int jt = 0; jt < 8; jt++) {
        floatx4 acc = {0.f, 0.f, 0.f, 0.f};
        #pragma unroll
        for (int kk = 0; kk < 4; kk++) {
            short8 bfr = *(const short8*)&Ws[jt * 16 + m][kk * 32 + quad * 8];
            acc = __builtin_amdgcn_mfma_f32_16x16x32_bf16(af[kk], bfr, acc, 0, 0, 0);
        }
        #pragma unroll
        for (int r = 0; r < 4; r++) {               // C/D: col=m, row=quad*4+r
            int n = n0 + w * 16 + quad * 4 + r;
            if (n < N_NODES)
                xl[(size_t)n * HC + jt * 16 + m] = __float2bfloat16(acc[r]);
        }
    }
    __syncthreads();                                // all waves done with Ws

    const unsigned* __restrict__ WuR = (const unsigned*)Wrb;
    for (int i = t; i < DIN * HC / 2; i += 256) {
        const unsigned u = WuR[i];
        const int l = 2 * i, c = l >> 7, j = l & 127;
        Ws[j][c]     = (unsigned short)(u & 0xFFFFu);
        Ws[j + 1][c] = (unsigned short)(u >> 16);
    }
    __syncthreads();

    #pragma unroll
    for (int jt = 0; jt < 8; jt++) {
        floatx4 acc = {0.f, 0.f, 0.f, 0.f};
        #pragma unroll
        for (int kk = 0; kk < 4; kk++) {
            short8 bfr = *(const short8*)&Ws[jt * 16 + m][kk * 32 + quad * 8];
            acc = __builtin_amdgcn_mfma_f32_16x16x32_bf16(af[kk], bfr, acc, 0, 0, 0);
        }
        #pragma unroll
        for (int r = 0; r < 4; r++) {
            int n = n0 + w * 16 + quad * 4 + r;
            if (n < N_NODES)
                xr[(size_t)n * HC + jt * 16 + m] = __float2bfloat16(acc[r]);
        }
    }
}

// Scan stage 1: block-local exclusive scan + per-block sums.
__global__ __launch_bounds__(SCAN_B) void k_scan1(
    const unsigned* __restrict__ deg, unsigned* __restrict__ offs,
    unsigned* __restrict__ bsum)
{
    __shared__ unsigned sh[SCAN_B];
    const int t = threadIdx.x, i = blockIdx.x * SCAN_B + t;
    const unsigned d = (i < N_NODES) ? deg[i] : 0u;
    sh[t] = d;
    __syncthreads();
    for (int off = 1; off < SCAN_B; off <<= 1) {
        unsigned v = (t >= off) ? sh[t - off] : 0u;
        __syncthreads();
        sh[t] += v;
        __syncthreads();
    }
    if (i < N_NODES) offs[i] = sh[t] - d;           // block-local exclusive
    if (t == SCAN_B - 1) bsum[blockIdx.x] = sh[t];
}

// Scan stage 2+3 fused: each block reduces its own prefix of bsum (196 u32,
// trivial) and adds the base; writes final offs + cursor.
__global__ __launch_bounds__(SCAN_B) void k_scan23(
    unsigned* __restrict__ offs, const unsigned* __restrict__ bsum,
    unsigned* __restrict__ cursor)
{
    __shared__ unsigned red[SCAN_B];
    const int t = threadIdx.x;
    red[t] = (t < SCAN_NB && t < blockIdx.x) ? bsum[t] : 0u;
    __syncthreads();
    for (int off = SCAN_B / 2; off > 0; off >>= 1) {
        if (t < off) red[t] += red[t + off];
        __syncthreads();
    }
    const unsigned base = red[0];
    const int i = blockIdx.x * SCAN_B + t;
    if (i < N_NODES) {
        const unsigned v = offs[i] + base;
        offs[i] = v;
        cursor[i] = v;
    }
    if (i == 0) offs[N_NODES] = N_EDGES;
}

// Bucket src ids by dst.
__global__ __launch_bounds__(256) void k_fill(
    const int* __restrict__ ei, unsigned* __restrict__ cursor,
    int* __restrict__ srcs)
{
    const int e = blockIdx.x * 256 + threadIdx.x;   // grid == E exactly
    const int dst = ei[N_EDGES + e];
    const unsigned pos = atomicAdd(&cursor[dst], 1u);
    srcs[pos] = ei[e];
}

// Fused logit + exp + aggregate + projection, single gather sweep,
// 8 edges per inner iteration (2 per q-slot, halves alternate edges).
// Lane = (half = lane>>5, cl = lane&31); lane owns cols 4cl..4cl+3
// (head h = cl>>3). All xw[] indices are compile-time constants —
// NO dynamic register-array indexing (round-8 scratch regression).
__global__ __launch_bounds__(256) void k_agg(
    const int* __restrict__ srcs, const unsigned* __restrict__ offs,
    const unsigned* __restrict__ xl2,   // bf16 xl as uint pairs [N][64]
    const unsigned* __restrict__ xr2,   // bf16 xr as uint pairs [N][64]
    const float* __restrict__ att,
    const float* __restrict__ Wp, const float* __restrict__ cvec,
    float* __restrict__ out)
{
    __shared__ float sWp[HC][DOUT];     // 16 KB
    __shared__ float srow[4][HC];
    const int t = threadIdx.x;
    for (int i = t; i < HC * DOUT; i += 256)
        ((float*)sWp)[i] = Wp[i];
    __syncthreads();

    const int w = t >> 6, lane = t & 63;
    const int node = blockIdx.x * 4 + w;
    const int half = lane >> 5, cl = lane & 31;
    const int c0 = 4 * cl;

    const uint2 xrw = *((const uint2*)(xr2 + node * 64) + cl);
    const float xr0 = bflo(xrw.x), xr1 = bfhi(xrw.x);
    const float xr2v = bflo(xrw.y), xr3 = bfhi(xrw.y);
    const float4 av = *(const float4*)(att + c0);

    const unsigned lo = offs[node], hi = offs[node + 1];
    float s_run = 0.f, acc0 = 0.f, acc1 = 0.f, acc2 = 0.f, acc3 = 0.f;

    for (unsigned base = lo; base < hi; base += 64) {
        const unsigned j = base + lane;
        const int srcj = (j < hi) ? srcs[j] : 0;
        const int cnt = (int)((hi - base < 64u) ? (hi - base) : 64u);
        uint2 xw[4];
        #pragma unroll
        for (int q = 0; q < 4; q++) {               // preload edges 0..7
            const int eq = 2 * q + half;
            const int sj = __shfl(srcj, eq, 64);
            xw[q] = *((const uint2*)(xl2 + ((unsigned)((eq < cnt) ? sj : 0) << 6)) + cl);
        }
        for (int i = 0; i < cnt; i += 8) {
            #pragma unroll
            for (int q = 0; q < 4; q++) {           // constant q -> registers
                const int eidx = i + 2 * q + half;
                const uint2 cur = xw[q];
                const int ii = eidx + 8;            // next edge for this slot
                const int sj = __shfl(srcj, ii & 63, 64);
                xw[q] = *((const uint2*)(xl2 + ((unsigned)((ii < cnt) ? sj : 0) << 6)) + cl);

                const float x0 = bflo(cur.x), x1 = bfhi(cur.x);
                const float x2 = bflo(cur.y), x3 = bfhi(cur.y);
                float v0 = x0 + xr0, v1 = x1 + xr1, v2 = x2 + xr2v, v3 = x3 + xr3;
                v0 = fmaxf(v0, NEG_SLOPE * v0);
                v1 = fmaxf(v1, NEG_SLOPE * v1);
                v2 = fmaxf(v2, NEG_SLOPE * v2);
                v3 = fmaxf(v3, NEG_SLOPE * v3);
                float p = av.x * v0 + av.y * v1 + av.z * v2 + av.w * v3;
                p += __shfl_xor(p, 1, 64);
                p += __shfl_xor(p, 2, 64);
                p += __shfl_xor(p, 4, 64);          // logit(edge eidx, head)
                const float e_ = (eidx < cnt) ? __expf(p) : 0.f;
                s_run += e_;
                acc0 += x0 * e_;
                acc1 += x1 * e_;
                acc2 += x2 * e_;
                acc3 += x3 * e_;
            }
        }
    }
    // combine the two halves (same cols, disjoint edge sets)
    s_run += __shfl_xor(s_run, 32, 64);
    acc0 += __shfl_xor(acc0, 32, 64);
    acc1 += __shfl_xor(acc1, 32, 64);
    acc2 += __shfl_xor(acc2, 32, 64);
    acc3 += __shfl_xor(acc3, 32, 64);
    const float rden = 1.f / (s_run + 1e-16f);

    if (half == 0) {
        float4 r = {acc0 * rden, acc1 * rden, acc2 * rden, acc3 * rden};
        *(float4*)&srow[w][c0] = r;
    }
    // same-wave LDS RAW: in-order DS pipe, no barrier needed
    const int jj = lane & 31;
    float pacc = 0.f;
    const int cb = half * 64;
    #pragma unroll 8
    for (int c = 0; c < 64; c++)
        pacc += srow[w][cb + c] * sWp[cb + c][jj];
    pacc += __shfl_down(pacc, 32, 64);
    if (lane < 32)
        out[(size_t)node * DOUT + jj] = pacc + cvec[jj];
}

extern "C" void kernel_launch(void* const* d_in, const int* in_sizes, int n_in,
                              void* d_out, int out_size, void* d_ws, size_t ws_size,
                              hipStream_t stream)
{
    const float* x    = (const float*)d_in[0];
    const int*   ei   = (const int*)d_in[1];
    const float* Wl   = (const float*)d_in[2];
    const float* Wr   = (const float*)d_in[3];
    const float* att  = (const float*)d_in[4];
    const float* bias = (const float*)d_in[5];
    const float* Wp   = (const float*)d_in[6];
    const float* bp   = (const float*)d_in[7];
    float* out = (float*)d_out;

    // workspace (~28.6 MB):
    // xl bf16[N*HC] | xr bf16[N*HC] | Wlb bf16[DIN*HC] | Wrb bf16[DIN*HC]
    // | cvec f32[32] | deg/cursor u32[N] | offs u32[N+1] | bsum u32[256]
    // | srcs i32[E]
    bf16* xl       = (bf16*)d_ws;
    bf16* xr       = xl + (size_t)N_NODES * HC;
    bf16* Wlb      = xr + (size_t)N_NODES * HC;
    bf16* Wrb      = Wlb + DIN * HC;
    float* cvec    = (float*)(Wrb + DIN * HC);
    unsigned* deg  = (unsigned*)(cvec + DOUT);
    unsigned* offs = deg + N_NODES;
    unsigned* bsum = offs + (N_NODES + 1);
    int* srcs      = (int*)(bsum + 256);

    hipMemsetAsync(deg, 0, (size_t)N_NODES * sizeof(unsigned), stream);

    k_prep<<<CNT_NB + 129, 256, 0, stream>>>(ei, deg, Wl, Wr, bias, Wp, bp,
                                             Wlb, Wrb, cvec);
    k_transform<<<(N_NODES + 63) / 64, 256, 0, stream>>>(x, Wlb, Wrb, xl, xr);
    k_scan1<<<SCAN_NB, SCAN_B, 0, stream>>>(deg, offs, bsum);
    k_scan23<<<SCAN_NB, SCAN_B, 0, stream>>>(offs, bsum, deg);  // deg = cursor
    k_fill<<<N_EDGES / 256, 256, 0, stream>>>(ei, deg, srcs);
    k_agg<<<N_NODES / 4, 256, 0, stream>>>(srcs, offs,
        (const unsigned*)xl, (const unsigned*)xr, att, Wp, cvec, out);
}